// Round 13
// baseline (623.248 us; speedup 1.0000x reference)
//
#include <hip/hip_runtime.h>
#include <hip/hip_bf16.h>

#define N_NODES 8192
#define F_IN    512
#define F_OUT   256
#define ALPHA   0.2f
#define CHUNK   32
#define NCHUNK  (N_NODES / CHUNK)   // 256
#define SEG     256                 // in-LDS sort segment length (1 elem/thread)
#define NMERGE  5                   // 256 -> 8192
#define BM      128
#define BN      64
#define BK      16
#define NBLK    256                 // mega grid size (1 block/CU)

// ---------------------------------------------------------------------------
// Kernel 1: h = x @ W   (frozen from round 9)
// ---------------------------------------------------------------------------
__global__ __launch_bounds__(512) void gemm_h(const float* __restrict__ A,
                                              const float* __restrict__ B,
                                              float* __restrict__ C) {
    __shared__ float As[BK][BM + 4];
    __shared__ float Bs[BK][BN + 4];
    const int t  = threadIdx.x;
    const int m0 = blockIdx.y * BM;
    const int n0 = blockIdx.x * BN;

    const int ar = t >> 2;
    const int ak = (t & 3) * 4;
    const int br = t >> 4;
    const int bc = (t & 15) * 4;
    const int ty = t >> 4;
    const int tx = t & 15;

    float4 aReg = *(const float4*)(A + (size_t)(m0 + ar) * F_IN + ak);
    float4 bReg = make_float4(0.f, 0.f, 0.f, 0.f);
    if (t < 256) bReg = *(const float4*)(B + (size_t)br * F_OUT + n0 + bc);

    float acc[4][4] = {};

    for (int k0 = 0; k0 < F_IN; k0 += BK) {
        __syncthreads();
        As[ak + 0][ar] = aReg.x;
        As[ak + 1][ar] = aReg.y;
        As[ak + 2][ar] = aReg.z;
        As[ak + 3][ar] = aReg.w;
        if (t < 256) *(float4*)(&Bs[br][bc]) = bReg;
        __syncthreads();
        if (k0 + BK < F_IN) {
            aReg = *(const float4*)(A + (size_t)(m0 + ar) * F_IN + k0 + BK + ak);
            if (t < 256) bReg = *(const float4*)(B + (size_t)(k0 + BK + br) * F_OUT + n0 + bc);
        }
        #pragma unroll
        for (int k = 0; k < BK; ++k) {
            const float4 a4 = *(const float4*)(&As[k][ty * 4]);
            const float4 b4 = *(const float4*)(&Bs[k][tx * 4]);
            acc[0][0] += a4.x * b4.x; acc[0][1] += a4.x * b4.y;
            acc[0][2] += a4.x * b4.z; acc[0][3] += a4.x * b4.w;
            acc[1][0] += a4.y * b4.x; acc[1][1] += a4.y * b4.y;
            acc[1][2] += a4.y * b4.z; acc[1][3] += a4.y * b4.w;
            acc[2][0] += a4.z * b4.x; acc[2][1] += a4.z * b4.y;
            acc[2][2] += a4.z * b4.z; acc[2][3] += a4.z * b4.w;
            acc[3][0] += a4.w * b4.x; acc[3][1] += a4.w * b4.y;
            acc[3][2] += a4.w * b4.z; acc[3][3] += a4.w * b4.w;
        }
    }
    #pragma unroll
    for (int r = 0; r < 4; ++r) {
        float4 o = make_float4(acc[r][0], acc[r][1], acc[r][2], acc[r][3]);
        *(float4*)(C + (size_t)(m0 + ty * 4 + r) * F_OUT + n0 + tx * 4) = o;
    }
}

// ---------------------------------------------------------------------------
// Two-level grid barrier. Layout per slot (512 uints, 2 KB):
//   [g*16]        : group arrival counters, g=0..7 (64B apart)
//   [128]         : root counter
//   [256 + g*16]  : per-group release flags
// Requires all NBLK blocks co-resident (cooperative launch guarantees it).
// ---------------------------------------------------------------------------
__device__ __forceinline__ void gbar(unsigned* barp, int slot) {
    __syncthreads();
    if (threadIdx.x == 0) {
        unsigned* s = barp + slot * 512;
        const int g = blockIdx.x & 7;
        __threadfence();   // release: prior writes visible at device scope
        const unsigned a = __hip_atomic_fetch_add(s + g * 16, 1u,
                              __ATOMIC_ACQ_REL, __HIP_MEMORY_SCOPE_AGENT) + 1u;
        if (a == (NBLK / 8)) {
            const unsigned r = __hip_atomic_fetch_add(s + 128, 1u,
                                  __ATOMIC_ACQ_REL, __HIP_MEMORY_SCOPE_AGENT) + 1u;
            if (r == 8u) {
                #pragma unroll
                for (int q = 0; q < 8; ++q)
                    __hip_atomic_store(s + 256 + q * 16, 1u,
                                       __ATOMIC_RELEASE, __HIP_MEMORY_SCOPE_AGENT);
            }
        }
        while (__hip_atomic_load(s + 256 + g * 16,
                                 __ATOMIC_ACQUIRE, __HIP_MEMORY_SCOPE_AGENT) == 0u) {
            __builtin_amdgcn_s_sleep(2);
        }
        __threadfence();   // acquire: invalidate stale cached lines
    }
    __syncthreads();
}

// ---------------------------------------------------------------------------
// Mega-kernel v2: custom barriers, 1-elem/thread sort, LDS-staged rows phase.
// ---------------------------------------------------------------------------
__global__ __launch_bounds__(256) void mega2_kernel(
        const float* __restrict__ h,
        const float* __restrict__ a,
        float* __restrict__ s1, float* __restrict__ s2,
        float* __restrict__ v0, int* __restrict__ p0,
        float* __restrict__ v1, int* __restrict__ p1,
        float* __restrict__ cneg, float* __restrict__ cpos,
        float* __restrict__ czn,  float* __restrict__ czp,
        unsigned* __restrict__ bar,
        float* __restrict__ out) {
    const int t    = threadIdx.x;
    const int bid  = blockIdx.x;
    const int wave = t >> 6;
    const int lane = t & 63;

    __shared__ float sv[SEG];          // sort vals (1KB)
    __shared__ int   sp[SEG];          // sort idx  (1KB)
    __shared__ float bn[NCHUNK];       // scan bufs
    __shared__ float bp[NCHUNK];
    __shared__ float sn[NCHUNK];
    __shared__ float sz[NCHUNK];
    __shared__ float vls[N_NODES];     // sorted-keys stage for phase 7 (32KB)

    // ---- phase 0: s1/s2 row dots (32 rows per block, 8 per wave) ----
    {
        const float4 a1 = *(const float4*)(a + lane * 4);
        const float4 a2 = *(const float4*)(a + F_OUT + lane * 4);
        #pragma unroll
        for (int r = 0; r < 8; ++r) {
            const int row = bid * 32 + wave * 8 + r;
            const float4 hv = *(const float4*)(h + (size_t)row * F_OUT + lane * 4);
            float d1 = hv.x * a1.x + hv.y * a1.y + hv.z * a1.z + hv.w * a1.w;
            float d2 = hv.x * a2.x + hv.y * a2.y + hv.z * a2.z + hv.w * a2.w;
            #pragma unroll
            for (int off = 32; off; off >>= 1) {
                d1 += __shfl_xor(d1, off);
                d2 += __shfl_xor(d2, off);
            }
            if (lane == 0) { s1[row] = d1; s2[row] = d2; }
        }
    }
    gbar(bar, 0);

    // ---- phase 1: blocks 0..31 bitonic-sort 256 elems each, 1 elem/thread --
    if (bid < N_NODES / SEG) {
        const int base = bid * SEG;
        sv[t] = s2[base + t];
        sp[t] = base + t;
        __syncthreads();
        for (int k = 2; k <= SEG; k <<= 1) {
            for (int j = k >> 1; j > 0; j >>= 1) {
                const int ixj = t ^ j;
                if (ixj > t) {
                    const bool up = ((t & k) == 0);
                    const float av = sv[t], bv = sv[ixj];
                    if (up ? (av > bv) : (av < bv)) {
                        sv[t] = bv; sv[ixj] = av;
                        const int pa = sp[t]; sp[t] = sp[ixj]; sp[ixj] = pa;
                    }
                }
                __syncthreads();
            }
        }
        v0[base + t] = sv[t];
        p0[base + t] = sp[t];
    }
    gbar(bar, 1);

    // ---- phases 2-6: rank-merge passes L=256..4096 (1 elem/thread) ----
    {
        const int gid = bid * 256 + t;
        #pragma unroll 1
        for (int pass = 0; pass < NMERGE; ++pass) {
            const int L = SEG << pass;
            const bool even = (pass & 1) == 0;
            const float* vin = even ? v0 : v1;
            const int*   pin = even ? p0 : p1;
            float*      vout = even ? v1 : v0;
            int*        pout = even ? p1 : p0;
            if (gid < N_NODES) {
                const int pair  = gid / (2 * L);
                const int local = gid - pair * 2 * L;
                const int beg   = pair * 2 * L;
                if (local < L) {                       // run A elem
                    const int i     = local;
                    const float key = vin[beg + i];
                    const int  idx  = pin[beg + i];
                    const float* Brun = vin + beg + L;
                    int lo = 0, hi = L;
                    while (lo < hi) {                  // lower_bound
                        const int mid = (lo + hi) >> 1;
                        if (Brun[mid] < key) lo = mid + 1; else hi = mid;
                    }
                    vout[beg + i + lo] = key;
                    pout[beg + i + lo] = idx;
                } else {                               // run B elem
                    const int i     = local - L;
                    const float key = vin[beg + L + i];
                    const int  idx  = pin[beg + L + i];
                    const float* Arun = vin + beg;
                    int lo = 0, hi = L;
                    while (lo < hi) {                  // upper_bound
                        const int mid = (lo + hi) >> 1;
                        if (Arun[mid] <= key) lo = mid + 1; else hi = mid;
                    }
                    vout[beg + lo + i] = key;
                    pout[beg + lo + i] = idx;
                }
            }
            gbar(bar, 2 + pass);
        }
    }
    // NMERGE=5 (odd) -> final sorted result in v1/p1

    // ---- phase 5: chunk sums (block = chunk c, thread = feature f) ----
    {
        const float M = v1[N_NODES - 1];
        float accN = 0.f, accP = 0.f, zn = 0.f, zp = 0.f;
        #pragma unroll 8
        for (int tt = 0; tt < CHUNK; ++tt) {
            const int j = bid * CHUNK + tt;
            const float vj = v1[j];
            const int pj   = p1[j];
            const float wn = __expf(ALPHA * vj);
            const float wp = __expf(vj - M);
            const float hv = h[(size_t)pj * F_OUT + t];
            accN += wn * hv; accP += wp * hv;
            zn += wn; zp += wp;
        }
        cneg[bid * F_OUT + t] = accN;
        cpos[bid * F_OUT + t] = accP;
        if (t == 0) { czn[bid] = zn; czp[bid] = zp; }
    }
    gbar(bar, 2 + NMERGE);

    // ---- phase 6: exclusive scans (block = feature f, thread = chunk c) ----
    {
        const float xn = cneg[(size_t)t * F_OUT + bid];
        const float xp = cpos[(size_t)t * F_OUT + bid];
        bn[t] = xn; bp[t] = xp;
        __syncthreads();
        #pragma unroll
        for (int off = 1; off < NCHUNK; off <<= 1) {
            const float an = (t >= off) ? bn[t - off] : 0.f;           // prefix
            const float ap = (t + off < NCHUNK) ? bp[t + off] : 0.f;   // suffix
            __syncthreads();
            bn[t] += an; bp[t] += ap;
            __syncthreads();
        }
        cneg[(size_t)t * F_OUT + bid] = bn[t] - xn;
        cpos[(size_t)t * F_OUT + bid] = bp[t] - xp;

        if (bid == 0) {   // scalar scans
            const float yn = czn[t];
            const float yp = czp[t];
            sn[t] = yn; sz[t] = yp;
            __syncthreads();
            #pragma unroll
            for (int off = 1; off < NCHUNK; off <<= 1) {
                const float an = (t >= off) ? sn[t - off] : 0.f;
                const float ap = (t + off < NCHUNK) ? sz[t + off] : 0.f;
                __syncthreads();
                sn[t] += an; sz[t] += ap;
                __syncthreads();
            }
            czn[t] = sn[t] - yn;
            czp[t] = sz[t] - yp;
        }
    }
    gbar(bar, 3 + NMERGE);

    // ---- phase 7: per-row output; v1 staged in LDS; rows unrolled x2 ----
    {
        for (int i = t; i < N_NODES; i += 256) vls[i] = v1[i];
        __syncthreads();
        const float M = vls[N_NODES - 1];
        #pragma unroll 2
        for (int r = 0; r < 8; ++r) {
            const int i = bid * 32 + wave * 8 + r;
            const float s1v = s1[i];

            const float thr = -s1v;
            int lo = 0, hi = N_NODES;
            while (lo < hi) {
                const int mid = (lo + hi) >> 1;
                if (vls[mid] < thr) lo = mid + 1; else hi = mid;
            }
            const int k = lo;
            const int c = min(k >> 5, NCHUNK - 1);
            const int start = c * CHUNK;

            const float4 bN = *(const float4*)(cneg + (size_t)c * F_OUT + lane * 4);
            const float4 bP = *(const float4*)(cpos + (size_t)c * F_OUT + lane * 4);
            float aN0 = bN.x, aN1 = bN.y, aN2 = bN.z, aN3 = bN.w;
            float aP0 = bP.x, aP1 = bP.y, aP2 = bP.z, aP3 = bP.w;
            float zn = czn[c];
            float zp = czp[c];

            #pragma unroll 8
            for (int tt = 0; tt < CHUNK; ++tt) {
                const int j = start + tt;
                const float vj = vls[j];
                const int pj   = p1[j];
                const float4 hv = *(const float4*)(h + (size_t)pj * F_OUT + lane * 4);
                if (j < k) {
                    const float wn = __expf(ALPHA * vj);
                    aN0 += wn * hv.x; aN1 += wn * hv.y; aN2 += wn * hv.z; aN3 += wn * hv.w;
                    zn += wn;
                } else {
                    const float wp = __expf(vj - M);
                    aP0 += wp * hv.x; aP1 += wp * hv.y; aP2 += wp * hv.z; aP3 += wp * hv.w;
                    zp += wp;
                }
            }

            const float x  = s1v + M;
            const float m  = (x >= 0.f) ? x : ALPHA * x;
            const float cp = __expf(x - m);
            const float cn = __expf(ALPHA * s1v - m);
            const float invZ = 1.0f / (cp * zp + cn * zn);

            float4 o;
            o.x = (cp * aP0 + cn * aN0) * invZ;
            o.y = (cp * aP1 + cn * aN1) * invZ;
            o.z = (cp * aP2 + cn * aN2) * invZ;
            o.w = (cp * aP3 + cn * aN3) * invZ;
            o.x = (o.x > 0.f) ? o.x : expm1f(o.x);
            o.y = (o.y > 0.f) ? o.y : expm1f(o.y);
            o.z = (o.z > 0.f) ? o.z : expm1f(o.z);
            o.w = (o.w > 0.f) ? o.w : expm1f(o.w);
            *(float4*)(out + (size_t)i * F_OUT + lane * 4) = o;
        }
    }
}

// ---------------------------------------------------------------------------
// Fallback path kernels, used only if ws_size is too small.
// ---------------------------------------------------------------------------
__global__ __launch_bounds__(256) void s12_kernel(const float* __restrict__ h,
                                                  const float* __restrict__ a,
                                                  float* __restrict__ s1,
                                                  float* __restrict__ s2) {
    const int wave = threadIdx.x >> 6;
    const int lane = threadIdx.x & 63;
    const int row  = blockIdx.x * 4 + wave;

    const float4 hv = *(const float4*)(h + (size_t)row * F_OUT + lane * 4);
    const float4 a1 = *(const float4*)(a + lane * 4);
    const float4 a2 = *(const float4*)(a + F_OUT + lane * 4);

    float p1 = hv.x * a1.x + hv.y * a1.y + hv.z * a1.z + hv.w * a1.w;
    float p2 = hv.x * a2.x + hv.y * a2.y + hv.z * a2.z + hv.w * a2.w;
    #pragma unroll
    for (int off = 32; off; off >>= 1) {
        p1 += __shfl_xor(p1, off);
        p2 += __shfl_xor(p2, off);
    }
    if (lane == 0) { s1[row] = p1; s2[row] = p2; }
}

__global__ __launch_bounds__(1024) void maxs2_kernel(const float* __restrict__ s2,
                                                     float* __restrict__ M) {
    __shared__ float red[1024];
    float m = -1e30f;
    for (int i = threadIdx.x; i < N_NODES; i += 1024) m = fmaxf(m, s2[i]);
    red[threadIdx.x] = m;
    __syncthreads();
    for (int s = 512; s; s >>= 1) {
        if (threadIdx.x < s) red[threadIdx.x] = fmaxf(red[threadIdx.x], red[threadIdx.x + s]);
        __syncthreads();
    }
    if (threadIdx.x == 0) M[0] = red[0];
}

__global__ __launch_bounds__(256) void aggregate_kernel(const float* __restrict__ h,
                                                        const float* __restrict__ s1,
                                                        const float* __restrict__ s2,
                                                        const float* __restrict__ Mptr,
                                                        float* __restrict__ out) {
    __shared__ float w_lds[32][33];
    __shared__ float s2t[32];
    __shared__ float s1_loc[32];
    __shared__ float m_loc[32];

    const int t  = threadIdx.x;
    const int i0 = blockIdx.x * 32;
    const float Mv = Mptr[0];

    if (t < 32) {
        const float s1v = s1[i0 + t];
        s1_loc[t] = s1v;
        const float x = s1v + Mv;
        m_loc[t] = (x >= 0.f) ? x : ALPHA * x;
    }
    __syncthreads();

    const int g  = t >> 6;
    const int fl = t & 63;
    const int f4 = fl * 4;

    float acc[8][4] = {};
    float zacc[8]   = {};

    for (int j0 = 0; j0 < N_NODES; j0 += 32) {
        __syncthreads();
        if (t < 32) s2t[t] = s2[j0 + t];
        __syncthreads();
        #pragma unroll
        for (int q = 0; q < 4; ++q) {
            const int idx = t + q * 256;
            const int il  = idx >> 5;
            const int jl  = idx & 31;
            float e = s1_loc[il] + s2t[jl];
            e = (e >= 0.f) ? e : ALPHA * e;
            w_lds[il][jl] = __expf(e - m_loc[il]);
        }
        __syncthreads();

        #pragma unroll 4
        for (int jl = 0; jl < 32; ++jl) {
            const float4 hv = *(const float4*)(h + (size_t)(j0 + jl) * F_OUT + f4);
            #pragma unroll
            for (int r = 0; r < 8; ++r) {
                const float w = w_lds[g * 8 + r][jl];
                acc[r][0] += w * hv.x;
                acc[r][1] += w * hv.y;
                acc[r][2] += w * hv.z;
                acc[r][3] += w * hv.w;
                zacc[r]   += w;
            }
        }
    }

    #pragma unroll
    for (int r = 0; r < 8; ++r) {
        const int i = i0 + g * 8 + r;
        const float inv = 1.0f / zacc[r];
        float4 o;
        o.x = acc[r][0] * inv; o.y = acc[r][1] * inv;
        o.z = acc[r][2] * inv; o.w = acc[r][3] * inv;
        o.x = (o.x > 0.f) ? o.x : expm1f(o.x);
        o.y = (o.y > 0.f) ? o.y : expm1f(o.y);
        o.z = (o.z > 0.f) ? o.z : expm1f(o.z);
        o.w = (o.w > 0.f) ? o.w : expm1f(o.w);
        *(float4*)(out + (size_t)i * F_OUT + f4) = o;
    }
}

// ---------------------------------------------------------------------------
extern "C" void kernel_launch(void* const* d_in, const int* in_sizes, int n_in,
                              void* d_out, int out_size, void* d_ws, size_t ws_size,
                              hipStream_t stream) {
    const float* x = (const float*)d_in[0];   // [8192,512]
    const float* W = (const float*)d_in[1];   // [512,256]
    const float* a = (const float*)d_in[2];   // [512,1]
    float* out = (float*)d_out;               // [8192,256]

    constexpr size_t SZ_H    = (size_t)N_NODES * F_OUT * 4;        // 8 MB
    constexpr size_t SZ_VEC  = (size_t)N_NODES * 4;                // 32 KB
    constexpr size_t SZ_CHNK = (size_t)NCHUNK * F_OUT * 4;         // 256 KB
    constexpr size_t SZ_CZ   = (size_t)NCHUNK * 4;                 // 1 KB
    constexpr size_t SZ_BAR  = 16 * 512 * 4;                       // 32 KB

    constexpr size_t OFF_H     = 0;
    constexpr size_t OFF_S1    = OFF_H + SZ_H;
    constexpr size_t OFF_S2    = OFF_S1 + SZ_VEC;
    constexpr size_t OFF_V0    = OFF_S2 + SZ_VEC;
    constexpr size_t OFF_P0    = OFF_V0 + SZ_VEC;
    constexpr size_t OFF_V1    = OFF_P0 + SZ_VEC;
    constexpr size_t OFF_P1    = OFF_V1 + SZ_VEC;
    constexpr size_t OFF_CZN   = OFF_P1 + SZ_VEC;
    constexpr size_t OFF_CZP   = OFF_CZN + SZ_CZ;
    constexpr size_t OFF_CNEG  = OFF_CZP + SZ_CZ;
    constexpr size_t OFF_CPOS  = OFF_CNEG + SZ_CHNK;
    constexpr size_t OFF_BAR   = OFF_CPOS + SZ_CHNK;
    constexpr size_t REQUIRED  = OFF_BAR + SZ_BAR;                 // ~8.9 MB

    char* ws = (char*)d_ws;
    float* h  = (float*)(ws + OFF_H);
    float* s1 = (float*)(ws + OFF_S1);
    float* s2 = (float*)(ws + OFF_S2);

    gemm_h<<<dim3(F_OUT / BN, N_NODES / BM), 512, 0, stream>>>(x, W, h);

    if (ws_size >= REQUIRED) {
        float* v0      = (float*)(ws + OFF_V0);
        int*   p0      = (int*)(ws + OFF_P0);
        float* v1      = (float*)(ws + OFF_V1);
        int*   p1      = (int*)(ws + OFF_P1);
        float* czn     = (float*)(ws + OFF_CZN);
        float* czp     = (float*)(ws + OFF_CZP);
        float* cneg    = (float*)(ws + OFF_CNEG);
        float* cpos    = (float*)(ws + OFF_CPOS);
        unsigned* bar  = (unsigned*)(ws + OFF_BAR);

        hipMemsetAsync(bar, 0, SZ_BAR, stream);   // zero barrier slots each call

        void* args[] = { (void*)&h, (void*)&a, (void*)&s1, (void*)&s2,
                         (void*)&v0, (void*)&p0, (void*)&v1, (void*)&p1,
                         (void*)&cneg, (void*)&cpos, (void*)&czn, (void*)&czp,
                         (void*)&bar, (void*)&out };
        hipLaunchCooperativeKernel((void*)mega2_kernel, dim3(NBLK), dim3(256),
                                   args, 0, stream);
    } else {
        // fallback: round-1 flash-style path (non-cooperative)
        float* M = (float*)(ws + OFF_V0);
        s12_kernel<<<N_NODES / 4, 256, 0, stream>>>(h, a, s1, s2);
        maxs2_kernel<<<1, 1024, 0, stream>>>(s2, M);
        aggregate_kernel<<<N_NODES / 32, 256, 0, stream>>>(h, s1, s2, M, out);
    }
}

// Round 14
// 158.970 us; speedup vs baseline: 3.9205x; 3.9205x over previous
//
#include <hip/hip_runtime.h>
#include <hip/hip_bf16.h>

#define N_NODES 8192
#define F_IN    512
#define F_OUT   256
#define ALPHA   0.2f
#define CHUNK   32
#define NCHUNK  (N_NODES / CHUNK)   // 256
#define SEG     1024                // seg_sort segment length
#define BM      128
#define BN      64
#define BK      16

// ---------------------------------------------------------------------------
// Kernel 1: h = x @ W  (R9-frozen GEMM) + fused s1/s2 epilogue.
// Each block reduces its acc tile vs a1/a2 slices and atomicAdds row partials.
// s1/s2 must be zeroed before launch (hipMemsetAsync).
// ---------------------------------------------------------------------------
__global__ __launch_bounds__(512) void gemm_s12(const float* __restrict__ A,
                                                const float* __restrict__ B,
                                                const float* __restrict__ attn,
                                                float* __restrict__ C,
                                                float* __restrict__ s1,
                                                float* __restrict__ s2) {
    __shared__ float As[BK][BM + 4];
    __shared__ float Bs[BK][BN + 4];
    const int t  = threadIdx.x;
    const int m0 = blockIdx.y * BM;
    const int n0 = blockIdx.x * BN;

    const int ar = t >> 2;
    const int ak = (t & 3) * 4;
    const int br = t >> 4;
    const int bc = (t & 15) * 4;
    const int ty = t >> 4;             // 0..31
    const int tx = t & 15;             // 0..15

    float4 aReg = *(const float4*)(A + (size_t)(m0 + ar) * F_IN + ak);
    float4 bReg = make_float4(0.f, 0.f, 0.f, 0.f);
    if (t < 256) bReg = *(const float4*)(B + (size_t)br * F_OUT + n0 + bc);

    float acc[4][4] = {};

    for (int k0 = 0; k0 < F_IN; k0 += BK) {
        __syncthreads();
        As[ak + 0][ar] = aReg.x;
        As[ak + 1][ar] = aReg.y;
        As[ak + 2][ar] = aReg.z;
        As[ak + 3][ar] = aReg.w;
        if (t < 256) *(float4*)(&Bs[br][bc]) = bReg;
        __syncthreads();
        if (k0 + BK < F_IN) {
            aReg = *(const float4*)(A + (size_t)(m0 + ar) * F_IN + k0 + BK + ak);
            if (t < 256) bReg = *(const float4*)(B + (size_t)(k0 + BK + br) * F_OUT + n0 + bc);
        }
        #pragma unroll
        for (int k = 0; k < BK; ++k) {
            const float4 a4 = *(const float4*)(&As[k][ty * 4]);
            const float4 b4 = *(const float4*)(&Bs[k][tx * 4]);
            acc[0][0] += a4.x * b4.x; acc[0][1] += a4.x * b4.y;
            acc[0][2] += a4.x * b4.z; acc[0][3] += a4.x * b4.w;
            acc[1][0] += a4.y * b4.x; acc[1][1] += a4.y * b4.y;
            acc[1][2] += a4.y * b4.z; acc[1][3] += a4.y * b4.w;
            acc[2][0] += a4.z * b4.x; acc[2][1] += a4.z * b4.y;
            acc[2][2] += a4.z * b4.z; acc[2][3] += a4.z * b4.w;
            acc[3][0] += a4.w * b4.x; acc[3][1] += a4.w * b4.y;
            acc[3][2] += a4.w * b4.z; acc[3][3] += a4.w * b4.w;
        }
    }
    #pragma unroll
    for (int r = 0; r < 4; ++r) {
        float4 o = make_float4(acc[r][0], acc[r][1], acc[r][2], acc[r][3]);
        *(float4*)(C + (size_t)(m0 + ty * 4 + r) * F_OUT + n0 + tx * 4) = o;
    }

    // fused s12 epilogue: partial dots of this block's 64-col slice
    const float4 a1v = *(const float4*)(attn + n0 + tx * 4);
    const float4 a2v = *(const float4*)(attn + F_OUT + n0 + tx * 4);
    #pragma unroll
    for (int r = 0; r < 4; ++r) {
        float p1 = acc[r][0] * a1v.x + acc[r][1] * a1v.y
                 + acc[r][2] * a1v.z + acc[r][3] * a1v.w;
        float p2 = acc[r][0] * a2v.x + acc[r][1] * a2v.y
                 + acc[r][2] * a2v.z + acc[r][3] * a2v.w;
        #pragma unroll
        for (int off = 8; off; off >>= 1) {   // reduce across the 16 tx lanes
            p1 += __shfl_xor(p1, off);
            p2 += __shfl_xor(p2, off);
        }
        if (tx == 0) {
            atomicAdd(&s1[m0 + ty * 4 + r], p1);
            atomicAdd(&s2[m0 + ty * 4 + r], p2);
        }
    }
}

// ---------------------------------------------------------------------------
// Kernel 2a: sort 8 segments of 1024 (val,idx) pairs in LDS (R9-frozen).
// ---------------------------------------------------------------------------
__global__ __launch_bounds__(1024) void seg_sort(const float* __restrict__ s2,
                                                 float* __restrict__ v,
                                                 int* __restrict__ p) {
    __shared__ float sv[SEG];
    __shared__ int   sp[SEG];
    const int t    = threadIdx.x;
    const int base = blockIdx.x * SEG;
    sv[t] = s2[base + t];
    sp[t] = base + t;
    __syncthreads();
    for (int k = 2; k <= SEG; k <<= 1) {
        for (int j = k >> 1; j > 0; j >>= 1) {
            const int ixj = t ^ j;
            if (ixj > t) {
                const bool up = ((t & k) == 0);
                const float av = sv[t], bv = sv[ixj];
                if (up ? (av > bv) : (av < bv)) {
                    sv[t] = bv; sv[ixj] = av;
                    const int pa = sp[t]; sp[t] = sp[ixj]; sp[ixj] = pa;
                }
            }
            __syncthreads();
        }
    }
    v[base + t] = sv[t];
    p[base + t] = sp[t];
}

// ---------------------------------------------------------------------------
// Kernel 2b: rank-merge adjacent sorted runs of length L into 2L (R9-frozen).
// ---------------------------------------------------------------------------
__global__ __launch_bounds__(256) void merge_pass(const float* __restrict__ vin,
                                                  const int* __restrict__ pin,
                                                  float* __restrict__ vout,
                                                  int* __restrict__ pout,
                                                  int L) {
    const int gid   = blockIdx.x * 256 + threadIdx.x;
    const int pair  = gid / (2 * L);
    const int local = gid - pair * 2 * L;
    const int beg   = pair * 2 * L;

    if (local < L) {
        const int i     = local;
        const float key = vin[beg + i];
        const int  idx  = pin[beg + i];
        const float* Brun = vin + beg + L;
        int lo = 0, hi = L;
        while (lo < hi) {                  // lower_bound
            const int mid = (lo + hi) >> 1;
            if (Brun[mid] < key) lo = mid + 1; else hi = mid;
        }
        vout[beg + i + lo] = key;
        pout[beg + i + lo] = idx;
    } else {
        const int i     = local - L;
        const float key = vin[beg + L + i];
        const int  idx  = pin[beg + L + i];
        const float* Arun = vin + beg;
        int lo = 0, hi = L;
        while (lo < hi) {                  // upper_bound
            const int mid = (lo + hi) >> 1;
            if (Arun[mid] <= key) lo = mid + 1; else hi = mid;
        }
        vout[beg + lo + i] = key;
        pout[beg + lo + i] = idx;
    }
}

// ---------------------------------------------------------------------------
// Kernel 3: chunk totals + PERMUTE h into sorted order.
// hs[j][f] = h[p[j]][f]  (gather once, sequential consumers downstream).
// ---------------------------------------------------------------------------
__global__ __launch_bounds__(256) void chunk_perm_sums(const float* __restrict__ h,
                                                       const float* __restrict__ v,
                                                       const int* __restrict__ p,
                                                       float* __restrict__ hs,
                                                       float* __restrict__ cneg,
                                                       float* __restrict__ cpos,
                                                       float* __restrict__ czn,
                                                       float* __restrict__ czp) {
    const int c = blockIdx.x;
    const int f = threadIdx.x;
    const float M = v[N_NODES - 1];
    float accN = 0.f, accP = 0.f, zn = 0.f, zp = 0.f;
    #pragma unroll 8
    for (int tt = 0; tt < CHUNK; ++tt) {
        const int j = c * CHUNK + tt;
        const float vj = v[j];
        const int pj   = p[j];
        const float wn = __expf(ALPHA * vj);
        const float wp = __expf(vj - M);
        const float hv = h[(size_t)pj * F_OUT + f];
        hs[(size_t)j * F_OUT + f] = hv;
        accN += wn * hv; accP += wp * hv;
        zn += wn; zp += wp;
    }
    cneg[c * F_OUT + f] = accN;
    cpos[c * F_OUT + f] = accP;
    if (f == 0) { czn[c] = zn; czp[c] = zp; }
}

// ---------------------------------------------------------------------------
// Kernel 4: exclusive scans of chunk totals (R9-frozen scan_cols).
// ---------------------------------------------------------------------------
__global__ __launch_bounds__(256) void scan_cols(float* __restrict__ cneg,
                                                 float* __restrict__ cpos,
                                                 float* __restrict__ czn,
                                                 float* __restrict__ czp) {
    const int f = blockIdx.x;
    const int c = threadIdx.x;
    __shared__ float bn[NCHUNK];
    __shared__ float bp[NCHUNK];

    const float xn = cneg[(size_t)c * F_OUT + f];
    const float xp = cpos[(size_t)c * F_OUT + f];
    bn[c] = xn; bp[c] = xp;
    __syncthreads();
    #pragma unroll
    for (int off = 1; off < NCHUNK; off <<= 1) {
        const float an = (c >= off) ? bn[c - off] : 0.f;
        const float ap = (c + off < NCHUNK) ? bp[c + off] : 0.f;
        __syncthreads();
        bn[c] += an; bp[c] += ap;
        __syncthreads();
    }
    cneg[(size_t)c * F_OUT + f] = bn[c] - xn;
    cpos[(size_t)c * F_OUT + f] = bp[c] - xp;

    if (blockIdx.x == 0) {
        __shared__ float sn[NCHUNK];
        __shared__ float sp_[NCHUNK];
        const float yn = czn[c];
        const float yp = czp[c];
        sn[c] = yn; sp_[c] = yp;
        __syncthreads();
        #pragma unroll
        for (int off = 1; off < NCHUNK; off <<= 1) {
            const float an = (c >= off) ? sn[c - off] : 0.f;
            const float ap = (c + off < NCHUNK) ? sp_[c + off] : 0.f;
            __syncthreads();
            sn[c] += an; sp_[c] += ap;
            __syncthreads();
        }
        czn[c] = sn[c] - yn;
        czp[c] = sp_[c] - yp;
    }
}

// ---------------------------------------------------------------------------
// Kernel 5: per-row output; tail reads PERMUTED hs sequentially (no p).
// ---------------------------------------------------------------------------
__global__ __launch_bounds__(256) void rows3_kernel(const float* __restrict__ s1,
                                                    const float* __restrict__ v,
                                                    const float* __restrict__ hs,
                                                    const float* __restrict__ cnegS,
                                                    const float* __restrict__ cposS,
                                                    const float* __restrict__ cznS,
                                                    const float* __restrict__ czpS,
                                                    float* __restrict__ out) {
    const int wave = threadIdx.x >> 6;
    const int lane = threadIdx.x & 63;
    const int i = blockIdx.x * 4 + wave;

    const float s1v = s1[i];
    const float M   = v[N_NODES - 1];

    const float thr = -s1v;
    int lo = 0, hi = N_NODES;
    while (lo < hi) {
        const int mid = (lo + hi) >> 1;
        if (v[mid] < thr) lo = mid + 1; else hi = mid;
    }
    const int k = lo;
    const int c = min(k >> 5, NCHUNK - 1);
    const int start = c * CHUNK;

    const float4 bN = *(const float4*)(cnegS + (size_t)c * F_OUT + lane * 4);
    const float4 bP = *(const float4*)(cposS + (size_t)c * F_OUT + lane * 4);
    float aN0 = bN.x, aN1 = bN.y, aN2 = bN.z, aN3 = bN.w;
    float aP0 = bP.x, aP1 = bP.y, aP2 = bP.z, aP3 = bP.w;
    float zn = cznS[c];
    float zp = czpS[c];

    #pragma unroll 8
    for (int tt = 0; tt < CHUNK; ++tt) {
        const int j = start + tt;
        const float vj = v[j];
        const float4 hv = *(const float4*)(hs + (size_t)j * F_OUT + lane * 4);
        if (j < k) {
            const float wn = __expf(ALPHA * vj);
            aN0 += wn * hv.x; aN1 += wn * hv.y; aN2 += wn * hv.z; aN3 += wn * hv.w;
            zn += wn;
        } else {
            const float wp = __expf(vj - M);
            aP0 += wp * hv.x; aP1 += wp * hv.y; aP2 += wp * hv.z; aP3 += wp * hv.w;
            zp += wp;
        }
    }

    const float x  = s1v + M;
    const float m  = (x >= 0.f) ? x : ALPHA * x;
    const float cp = __expf(x - m);
    const float cn = __expf(ALPHA * s1v - m);
    const float invZ = 1.0f / (cp * zp + cn * zn);

    float4 o;
    o.x = (cp * aP0 + cn * aN0) * invZ;
    o.y = (cp * aP1 + cn * aN1) * invZ;
    o.z = (cp * aP2 + cn * aN2) * invZ;
    o.w = (cp * aP3 + cn * aN3) * invZ;
    o.x = (o.x > 0.f) ? o.x : expm1f(o.x);
    o.y = (o.y > 0.f) ? o.y : expm1f(o.y);
    o.z = (o.z > 0.f) ? o.z : expm1f(o.z);
    o.w = (o.w > 0.f) ? o.w : expm1f(o.w);
    *(float4*)(out + (size_t)i * F_OUT + lane * 4) = o;
}

// ---------------------------------------------------------------------------
// Fallback path kernels (need only ~8.6 MB ws).
// ---------------------------------------------------------------------------
__global__ __launch_bounds__(1024) void maxs2_kernel(const float* __restrict__ s2,
                                                     float* __restrict__ M) {
    __shared__ float red[1024];
    float m = -1e30f;
    for (int i = threadIdx.x; i < N_NODES; i += 1024) m = fmaxf(m, s2[i]);
    red[threadIdx.x] = m;
    __syncthreads();
    for (int s = 512; s; s >>= 1) {
        if (threadIdx.x < s) red[threadIdx.x] = fmaxf(red[threadIdx.x], red[threadIdx.x + s]);
        __syncthreads();
    }
    if (threadIdx.x == 0) M[0] = red[0];
}

__global__ __launch_bounds__(256) void aggregate_kernel(const float* __restrict__ h,
                                                        const float* __restrict__ s1,
                                                        const float* __restrict__ s2,
                                                        const float* __restrict__ Mptr,
                                                        float* __restrict__ out) {
    __shared__ float w_lds[32][33];
    __shared__ float s2t[32];
    __shared__ float s1_loc[32];
    __shared__ float m_loc[32];

    const int t  = threadIdx.x;
    const int i0 = blockIdx.x * 32;
    const float Mv = Mptr[0];

    if (t < 32) {
        const float s1v = s1[i0 + t];
        s1_loc[t] = s1v;
        const float x = s1v + Mv;
        m_loc[t] = (x >= 0.f) ? x : ALPHA * x;
    }
    __syncthreads();

    const int g  = t >> 6;
    const int fl = t & 63;
    const int f4 = fl * 4;

    float acc[8][4] = {};
    float zacc[8]   = {};

    for (int j0 = 0; j0 < N_NODES; j0 += 32) {
        __syncthreads();
        if (t < 32) s2t[t] = s2[j0 + t];
        __syncthreads();
        #pragma unroll
        for (int q = 0; q < 4; ++q) {
            const int idx = t + q * 256;
            const int il  = idx >> 5;
            const int jl  = idx & 31;
            float e = s1_loc[il] + s2t[jl];
            e = (e >= 0.f) ? e : ALPHA * e;
            w_lds[il][jl] = __expf(e - m_loc[il]);
        }
        __syncthreads();

        #pragma unroll 4
        for (int jl = 0; jl < 32; ++jl) {
            const float4 hv = *(const float4*)(h + (size_t)(j0 + jl) * F_OUT + f4);
            #pragma unroll
            for (int r = 0; r < 8; ++r) {
                const float w = w_lds[g * 8 + r][jl];
                acc[r][0] += w * hv.x;
                acc[r][1] += w * hv.y;
                acc[r][2] += w * hv.z;
                acc[r][3] += w * hv.w;
                zacc[r]   += w;
            }
        }
    }

    #pragma unroll
    for (int r = 0; r < 8; ++r) {
        const int i = i0 + g * 8 + r;
        const float inv = 1.0f / zacc[r];
        float4 o;
        o.x = acc[r][0] * inv; o.y = acc[r][1] * inv;
        o.z = acc[r][2] * inv; o.w = acc[r][3] * inv;
        o.x = (o.x > 0.f) ? o.x : expm1f(o.x);
        o.y = (o.y > 0.f) ? o.y : expm1f(o.y);
        o.z = (o.z > 0.f) ? o.z : expm1f(o.z);
        o.w = (o.w > 0.f) ? o.w : expm1f(o.w);
        *(float4*)(out + (size_t)i * F_OUT + f4) = o;
    }
}

// ---------------------------------------------------------------------------
extern "C" void kernel_launch(void* const* d_in, const int* in_sizes, int n_in,
                              void* d_out, int out_size, void* d_ws, size_t ws_size,
                              hipStream_t stream) {
    const float* x = (const float*)d_in[0];   // [8192,512]
    const float* W = (const float*)d_in[1];   // [512,256]
    const float* a = (const float*)d_in[2];   // [512,1]
    float* out = (float*)d_out;               // [8192,256]

    constexpr size_t SZ_H    = (size_t)N_NODES * F_OUT * 4;        // 8 MB
    constexpr size_t SZ_VEC  = (size_t)N_NODES * 4;                // 32 KB
    constexpr size_t SZ_CHNK = (size_t)NCHUNK * F_OUT * 4;         // 256 KB
    constexpr size_t SZ_CZ   = (size_t)NCHUNK * 4;                 // 1 KB

    constexpr size_t OFF_H     = 0;
    constexpr size_t OFF_S1    = OFF_H + SZ_H;
    constexpr size_t OFF_S2    = OFF_S1 + SZ_VEC;
    constexpr size_t OFF_V0    = OFF_S2 + SZ_VEC;
    constexpr size_t OFF_P0    = OFF_V0 + SZ_VEC;
    constexpr size_t OFF_V1    = OFF_P0 + SZ_VEC;
    constexpr size_t OFF_P1    = OFF_V1 + SZ_VEC;
    constexpr size_t OFF_CZN   = OFF_P1 + SZ_VEC;
    constexpr size_t OFF_CZP   = OFF_CZN + SZ_CZ;
    constexpr size_t OFF_CNEG  = OFF_CZP + SZ_CZ;
    constexpr size_t OFF_CPOS  = OFF_CNEG + SZ_CHNK;
    constexpr size_t OFF_HS    = OFF_CPOS + SZ_CHNK;
    constexpr size_t REQUIRED  = OFF_HS + SZ_H;                    // ~16.8 MB

    char* ws = (char*)d_ws;
    float* h  = (float*)(ws + OFF_H);
    float* s1 = (float*)(ws + OFF_S1);
    float* s2 = (float*)(ws + OFF_S2);

    // zero s1/s2 accumulators (required by the fused atomic epilogue)
    hipMemsetAsync(s1, 0, 2 * SZ_VEC, stream);

    gemm_s12<<<dim3(F_OUT / BN, N_NODES / BM), 512, 0, stream>>>(x, W, a, h, s1, s2);

    if (ws_size >= REQUIRED) {
        float* v0    = (float*)(ws + OFF_V0);
        int*   p0    = (int*)(ws + OFF_P0);
        float* v1    = (float*)(ws + OFF_V1);
        int*   p1    = (int*)(ws + OFF_P1);
        float* czn   = (float*)(ws + OFF_CZN);
        float* czp   = (float*)(ws + OFF_CZP);
        float* cneg  = (float*)(ws + OFF_CNEG);
        float* cpos  = (float*)(ws + OFF_CPOS);
        float* hs    = (float*)(ws + OFF_HS);

        // parallel sort: 8 LDS segment sorts, then 3 rank-merge passes
        seg_sort<<<N_NODES / SEG, SEG, 0, stream>>>(s2, v0, p0);
        merge_pass<<<N_NODES / 256, 256, 0, stream>>>(v0, p0, v1, p1, 1024);
        merge_pass<<<N_NODES / 256, 256, 0, stream>>>(v1, p1, v0, p0, 2048);
        merge_pass<<<N_NODES / 256, 256, 0, stream>>>(v0, p0, v1, p1, 4096);

        chunk_perm_sums<<<NCHUNK, 256, 0, stream>>>(h, v1, p1, hs,
                                                    cneg, cpos, czn, czp);
        scan_cols<<<F_OUT, NCHUNK, 0, stream>>>(cneg, cpos, czn, czp);
        rows3_kernel<<<N_NODES / 4, 256, 0, stream>>>(s1, v1, hs,
                                                      cneg, cpos, czn, czp, out);
    } else {
        // fallback: round-1 flash-style path
        float* M = (float*)(ws + OFF_V0);
        maxs2_kernel<<<1, 1024, 0, stream>>>(s2, M);
        aggregate_kernel<<<N_NODES / 32, 256, 0, stream>>>(h, s1, s2, M, out);
    }
}